// Round 3
// baseline (129.568 us; speedup 1.0000x reference)
//
#include <hip/hip_runtime.h>
#include <hip/hip_bf16.h>

// Causal attention, B=2 NH=16 T=2048 D=64, fp32 I/O.
// R15 = R14 (4 waves, 17/17/16/16, single-V, CEXP-folded Kb, setprio) with a
// CROSS-STEP SOFTWARE PIPELINE (grid caps waves at 2/SIMD, so the win must be
// intra-wave ILP):
//   iter t:  softmax(t) [sa from last iter]  ->  pfr + lgkm0
//         -> stage K(t+2) into Kcur (P consumed; overlay buffer freed)
//         -> S(t+1) MFMAs from Knxt (independent of softmax; overlaps VALU)
//         -> vf reads + stage V(t+1)  ->  PV(t)
//   sa single-banked: consumed at iter top, rewritten by S(t+1) via mfma(C=0).
// vmcnt ledger (steady, issue order K(t+2) then V(t+1); entering: K(t+1),V(t)):
//   vmcnt(8) before kf reads = K(t+1) landed; vmcnt(4) before vf = V(t) landed;
//   tail: (4)/(0). Prologue issues K(t0),K(t0+1),V(t0) to preserve age order.
// Park state (36 VGPRs cold) moved to laundered scratch (one-time 144B/lane).

typedef __bf16 bf16;
typedef __bf16 bf16x4 __attribute__((ext_vector_type(4)));
typedef __bf16 bf16x8 __attribute__((ext_vector_type(8)));
typedef float floatx4 __attribute__((ext_vector_type(4)));

#define T_SEQ 2048
#define DH 64
#define TKS 32
#define BHN 32
#define CEXP 0.18033688011112042f  // (1/sqrt(64)) * log2(e)

__device__ __forceinline__ void gload16(const bf16* g, bf16* l) {
    __builtin_amdgcn_global_load_lds(
        (const __attribute__((address_space(1))) void*)g,
        (__attribute__((address_space(3))) void*)l, 16, 0, 0);
}

// ---------------- fused prepass (CEXP folded into Kb) ----------------
__global__ __launch_bounds__(256) void prep(const float* __restrict__ K,
                                            const float* __restrict__ V,
                                            bf16* __restrict__ Kb,
                                            bf16* __restrict__ Vt) {
    const int bid = (int)blockIdx.x;
    const int tid = (int)threadIdx.x;
    if (bid < 512) {
        size_t i = ((size_t)bid * 256 + tid) * 8;
        #pragma unroll
        for (int it = 0; it < 4; ++it) {
            float4 a = *(const float4*)(K + i + 0);
            float4 b = *(const float4*)(K + i + 4);
            bf16x8 o;
            o[0]=(bf16)(a.x*CEXP); o[1]=(bf16)(a.y*CEXP); o[2]=(bf16)(a.z*CEXP); o[3]=(bf16)(a.w*CEXP);
            o[4]=(bf16)(b.x*CEXP); o[5]=(bf16)(b.y*CEXP); o[6]=(bf16)(b.z*CEXP); o[7]=(bf16)(b.w*CEXP);
            *(bf16x8*)(Kb + i) = o;
            i += (size_t)512 * 256 * 8;
        }
        return;
    }
    __shared__ bf16 tile[2][64][72];
    const int vb = bid - 512;
    const int bh = vb & (BHN - 1);
    const int tp = (vb >> 5) * 128;
    #pragma unroll
    for (int tt = 0; tt < 2; ++tt) {
        const int r = tid >> 2;
        const int c = (tid & 3) * 16;
        const float* s = V + ((size_t)bh * T_SEQ + tp + tt * 64 + r) * DH + c;
        float4 f0 = *(const float4*)(s + 0);
        float4 f1 = *(const float4*)(s + 4);
        float4 f2 = *(const float4*)(s + 8);
        float4 f3 = *(const float4*)(s + 12);
        bf16x8 p0, p1;
        p0[0]=(bf16)f0.x; p0[1]=(bf16)f0.y; p0[2]=(bf16)f0.z; p0[3]=(bf16)f0.w;
        p0[4]=(bf16)f1.x; p0[5]=(bf16)f1.y; p0[6]=(bf16)f1.z; p0[7]=(bf16)f1.w;
        p1[0]=(bf16)f2.x; p1[1]=(bf16)f2.y; p1[2]=(bf16)f2.z; p1[3]=(bf16)f2.w;
        p1[4]=(bf16)f3.x; p1[5]=(bf16)f3.y; p1[6]=(bf16)f3.z; p1[7]=(bf16)f3.w;
        *(bf16x8*)&tile[tt][r][c + 0] = p0;
        *(bf16x8*)&tile[tt][r][c + 8] = p1;
    }
    __syncthreads();
    #pragma unroll
    for (int tt = 0; tt < 2; ++tt) {
        const int d   = tid >> 2;
        const int tch = (tid & 3) * 16;
        bf16x8 o0, o1;
        #pragma unroll
        for (int j = 0; j < 8; ++j) { o0[j] = tile[tt][tch + j][d]; o1[j] = tile[tt][tch + 8 + j][d]; }
        bf16* o = Vt + ((size_t)bh * DH + d) * T_SEQ + tp + tt * 64 + tch;
        *(bf16x8*)(o + 0) = o0;
        *(bf16x8*)(o + 8) = o1;
    }
}

// ---------------- main flash kernel ----------------
__global__ __launch_bounds__(256, 2)
void fa_fwd(const float* __restrict__ Qg, const bf16* __restrict__ Kb,
            const bf16* __restrict__ Vt, float* __restrict__ Og)
{
    __shared__ __align__(16) bf16 smem[24576];   // 48 KB = 4 waves x 12 KB

    const int gid = (int)blockIdx.x;
    const int bh  = gid & (BHN - 1);
    const int m   = gid >> 5;                    // 0..15
    const int B   = 64 - 2 * m;                  // heavy tile count (>=34)
    const int qh  = (31 - m) * 64;
    const int ql  = m * 64;

    const int tid  = (int)threadIdx.x;
    const int wave = tid >> 6;
    const int lane = tid & 63;
    const int quad = lane >> 4;
    const int l16  = lane & 15;
    const int psw  = (l16 >> 1) & 3;

    const int tw0 = (wave < 2) ? wave * 17 : 34 + (wave - 2) * 16;
    const int tw1 = tw0 + ((wave < 2) ? 17 : 16);

    bf16* W = smem + wave * 6144;

    const bf16* Kbh = Kb + (size_t)bh * (T_SEQ * DH);
    const bf16* Vbh = Vt + (size_t)bh * (DH * T_SEQ);
    const size_t qrb = (size_t)bh * T_SEQ;

    // staging lane constants
    const int rl  = lane >> 3;
    const int kch = (lane & 7) ^ (rl & 7);
    const int vr  = lane >> 2;
    const int vch = (lane & 3) ^ ((lane >> 3) & 3);

    // park state in scratch (laundered pointer => memory-backed): frees ~36 VGPRs.
    uint pbuf[36];
    uint* pp = pbuf;
    asm volatile("" : "+v"(pp));

    bool heavyNow = (tw0 < B);
    int  qbase    = heavyNow ? qh : ql;
    bool hasPark  = false;

    bf16x8 qb[4][2];
    auto loadQ = [&](int qb0) {
        #pragma unroll
        for (int nt = 0; nt < 4; ++nt) {
            const int qrow = qb0 + nt * 16 + l16;
            #pragma unroll
            for (int kk = 0; kk < 2; ++kk) {
                const float* s = Qg + (qrb + qrow) * DH + kk * 32 + quad * 8;
                float4 f0 = *(const float4*)(s);
                float4 f1 = *(const float4*)(s + 4);
                bf16x8 t;
                t[0]=(bf16)f0.x; t[1]=(bf16)f0.y; t[2]=(bf16)f0.z; t[3]=(bf16)f0.w;
                t[4]=(bf16)f1.x; t[5]=(bf16)f1.y; t[6]=(bf16)f1.z; t[7]=(bf16)f1.w;
                qb[nt][kk] = t;
            }
        }
    };
    loadQ(qbase);

    floatx4 oacc[4][4];
    #pragma unroll
    for (int mt = 0; mt < 4; ++mt)
        #pragma unroll
        for (int nt = 0; nt < 4; ++nt) oacc[mt][nt] = (floatx4){0.f,0.f,0.f,0.f};
    float lpart[4] = {0.f, 0.f, 0.f, 0.f};

    auto kTileOf = [&](int t) { return (t < B) ? t : (t - B); };

    auto stageK = [&](int kt, bf16* dst) {
        const bf16* kg = Kbh + (size_t)kt * TKS * DH;
        #pragma unroll
        for (int g = 0; g < 4; ++g)
            gload16(kg + (size_t)(g * 8 + rl) * DH + kch * 8, dst + g * 512);
    };
    auto stageV = [&](int kt, bf16* dst) {
        const bf16* vg = Vbh + kt * TKS;
        #pragma unroll
        for (int g = 0; g < 4; ++g)
            gload16(vg + (size_t)(g * 16 + vr) * T_SEQ + vch * 8, dst + g * 512);
    };

    const floatx4 zf4 = {0.f, 0.f, 0.f, 0.f};
    floatx4 sa[2][4];
    auto computeS = [&](const bf16* Kbuf) {
        #pragma unroll
        for (int kk = 0; kk < 2; ++kk)
            #pragma unroll
            for (int mt = 0; mt < 2; ++mt) {
                bf16x8 kf = *(const bf16x8*)&Kbuf[(mt * 16 + l16) * 64 + (((kk * 4 + quad) ^ (l16 & 7)) * 8)];
                #pragma unroll
                for (int nt = 0; nt < 4; ++nt)
                    sa[mt][nt] = __builtin_amdgcn_mfma_f32_16x16x32_bf16(
                        kf, qb[nt][kk], (kk == 0) ? zf4 : sa[mt][nt], 0, 0, 0);
            }
    };

    // ---- prologue: stage K(t0), K(t0+1), V(t0) (age order matters) ----
    stageK(kTileOf(tw0), W);
    stageK(kTileOf(tw0 + 1), W + 2048);          // strips are >=16 steps
    stageV(kTileOf(tw0), W + 4096);
    __builtin_amdgcn_s_waitcnt(0x0F78);          // vmcnt(8): K(t0) landed
    computeS(W);                                 // S(t0); outstanding [K(t0+1), V(t0)]
    int cur = 0;                                 // K(t) lives in buf[cur]

    for (int t = tw0; t < tw1; ++t) {
        const bool hasD = (t + 1 < tw1);
        const bool hasC = (t + 2 < tw1);
        if (heavyNow && t + 1 == B) loadQ(ql);   // S(t+1) below needs light Q

        bf16* Kcur = W + cur * 2048;             // held K(t); now P overlay target
        bf16* Knxt = W + (cur ^ 1) * 2048;       // holds K(t+1)
        bf16* Vb   = W + 4096;
        const int k0 = kTileOf(t) * TKS;

        // ---- a. causal mask (diagonal band) on sa = S(t) ----
        if (k0 + TKS - 1 > qbase) {
            #pragma unroll
            for (int mt = 0; mt < 2; ++mt)
                #pragma unroll
                for (int nt = 0; nt < 4; ++nt) {
                    const int qg = qbase + nt * 16 + l16;
                    #pragma unroll
                    for (int r = 0; r < 4; ++r) {
                        const int keyg = k0 + mt * 16 + quad * 4 + r;
                        if (keyg > qg) sa[mt][nt][r] = -INFINITY;
                    }
                }
        }
        // ---- exp2 + P writes into Kcur overlay ----
        #pragma unroll
        for (int mt = 0; mt < 2; ++mt)
            #pragma unroll
            for (int nt = 0; nt < 4; ++nt) {
                bf16x4 w;
                #pragma unroll
                for (int r = 0; r < 4; ++r) {
                    const float pv = __builtin_amdgcn_exp2f(sa[mt][nt][r]);
                    lpart[nt] += pv;
                    w[r] = (bf16)pv;
                }
                const int slot = (mt * 2 + (quad >> 1)) ^ psw;
                *(bf16x4*)&Kcur[(nt * 16 + l16) * 32 + slot * 8 + (quad & 1) * 4] = w;
            }
        // ---- b. P^T fragments; drain DS so K(t+2) DMA can't clobber P ----
        bf16x8 pfr[4];
        #pragma unroll
        for (int nt = 0; nt < 4; ++nt)
            pfr[nt] = *(const bf16x8*)&Kcur[(nt * 16 + l16) * 32 + ((quad ^ psw) * 8)];
        __builtin_amdgcn_s_waitcnt(0xC07F);      // lgkmcnt(0)
        // ---- c. stage K(t+2) into Kcur ----
        if (hasC) stageK(kTileOf(t + 2), Kcur);
        // ---- d. S(t+1) from Knxt (overlaps softmax VALU above) ----
        if (hasD) {
            if (hasC) __builtin_amdgcn_s_waitcnt(0x0F78);  // vmcnt(8): K(t+1) landed
            else      __builtin_amdgcn_s_waitcnt(0x0F74);  // vmcnt(4): K(t+1) landed
            __builtin_amdgcn_s_setprio(1);
            computeS(Knxt);
            __builtin_amdgcn_s_setprio(0);
        }
        // ---- e. V(t) frags, then stage V(t+1) into the SAME buffer ----
        if (hasC) __builtin_amdgcn_s_waitcnt(0x0F74);      // vmcnt(4): V(t) landed
        else      __builtin_amdgcn_s_waitcnt(0x0F70);      // vmcnt(0)
        bf16x8 vf[4];
        #pragma unroll
        for (int mt = 0; mt < 4; ++mt)
            vf[mt] = *(const bf16x8*)&Vb[(mt * 16 + l16) * 32 + ((quad ^ psw) * 8)];
        if (hasD) {
            __builtin_amdgcn_s_waitcnt(0xC07F);  // lgkmcnt(0): vf in regs
            stageV(kTileOf(t + 1), Vb);          // safe: V(t) consumed
        }
        // ---- f. O^T += V^T.P^T ----
        __builtin_amdgcn_s_setprio(1);
        #pragma unroll
        for (int mt = 0; mt < 4; ++mt) {
            #pragma unroll
            for (int nt = 0; nt < 4; ++nt)
                oacc[mt][nt] = __builtin_amdgcn_mfma_f32_16x16x32_bf16(vf[mt], pfr[nt], oacc[mt][nt], 0, 0, 0);
        }
        __builtin_amdgcn_s_setprio(0);
        // ---- g. park heavy -> switch to light (after last heavy PV) ----
        if (heavyNow && t + 1 == B) {
            #pragma unroll
            for (int f = 0; f < 16; ++f) {
                bf16x4 w;
                #pragma unroll
                for (int e = 0; e < 4; ++e) w[e] = (bf16)oacc[f >> 2][f & 3][e];
                uint2 u; __builtin_memcpy(&u, &w, 8);
                pp[f * 2] = u.x; pp[f * 2 + 1] = u.y;
            }
            #pragma unroll
            for (int nt = 0; nt < 4; ++nt) {
                pp[32 + nt] = __float_as_uint(lpart[nt]);
                lpart[nt] = 0.f;
            }
            #pragma unroll
            for (int mt = 0; mt < 4; ++mt)
                #pragma unroll
                for (int nt = 0; nt < 4; ++nt) oacc[mt][nt] = (floatx4){0.f,0.f,0.f,0.f};
            hasPark = true;
            heavyNow = false;
            qbase = ql;
        }
        cur ^= 1;
    }

    // ================= end combine (R12-proven layout, fits 48 KB) =========
    __syncthreads();
    const bool hH = (tw0 < B);
    const bool hL = (tw1 > B);
    if (wave >= 1 && hH) {
        bf16* a = smem + (wave - 1) * 4608;
        float* al = (float*)(a + 4096);
        #pragma unroll
        for (int f = 0; f < 16; ++f) {
            bf16x4 w;
            if (hasPark) {
                uint2 u; u.x = pp[f * 2]; u.y = pp[f * 2 + 1];
                __builtin_memcpy(&w, &u, 8);
            } else {
                #pragma unroll
                for (int e = 0; e < 4; ++e) w[e] = (bf16)oacc[f >> 2][f & 3][e];
            }
            *(bf16x4*)&a[(f * 64 + lane) * 4] = w;
        }
        #pragma unroll
        for (int nt = 0; nt < 4; ++nt)
            al[nt * 64 + lane] = hasPark ? __uint_as_float(pp[32 + nt]) : lpart[nt];
    }
    if (wave >= 2 && hL) {
        bf16* a = smem + (wave + 1) * 4608;      // wave2->area3, wave3->area4
        float* al = (float*)(a + 4096);
        #pragma unroll
        for (int f = 0; f < 16; ++f) {
            bf16x4 w;
            #pragma unroll
            for (int e = 0; e < 4; ++e) w[e] = (bf16)oacc[f >> 2][f & 3][e];
            *(bf16x4*)&a[(f * 64 + lane) * 4] = w;
        }
        #pragma unroll
        for (int nt = 0; nt < 4; ++nt)
            al[nt * 64 + lane] = lpart[nt];
    }
    __syncthreads();

    if (wave <= 1) {
        int qfin;
        if (wave == 0) {
            qfin = qh;
            const int nA = (B > 50) ? 3 : ((B > 34) ? 2 : 1);
            for (int i = 0; i < nA; ++i) {
                const bf16* a = smem + i * 4608;
                const float* al = (const float*)(a + 4096);
                #pragma unroll
                for (int f = 0; f < 16; ++f) {
                    bf16x4 w = *(const bf16x4*)&a[(f * 64 + lane) * 4];
                    #pragma unroll
                    for (int e = 0; e < 4; ++e) oacc[f >> 2][f & 3][e] += (float)w[e];
                }
                #pragma unroll
                for (int nt = 0; nt < 4; ++nt) lpart[nt] += al[nt * 64 + lane];
            }
        } else {
            qfin = ql;
            #pragma unroll
            for (int mt = 0; mt < 4; ++mt)
                #pragma unroll
                for (int nt = 0; nt < 4; ++nt) oacc[mt][nt] = (floatx4){0.f,0.f,0.f,0.f};
            #pragma unroll
            for (int nt = 0; nt < 4; ++nt) lpart[nt] = 0.f;
            const int i0 = (B < 50) ? 3 : 4;
            for (int i = i0; i <= 4; ++i) {
                const bf16* a = smem + i * 4608;
                const float* al = (const float*)(a + 4096);
                #pragma unroll
                for (int f = 0; f < 16; ++f) {
                    bf16x4 w = *(const bf16x4*)&a[(f * 64 + lane) * 4];
                    #pragma unroll
                    for (int e = 0; e < 4; ++e) oacc[f >> 2][f & 3][e] += (float)w[e];
                }
                #pragma unroll
                for (int nt = 0; nt < 4; ++nt) lpart[nt] += al[nt * 64 + lane];
            }
        }
        float invl[4];
        #pragma unroll
        for (int nt = 0; nt < 4; ++nt) {
            float v = lpart[nt];
            v += __shfl_xor(v, 16);
            v += __shfl_xor(v, 32);
            invl[nt] = 1.0f / v;
        }
        #pragma unroll
        for (int nt = 0; nt < 4; ++nt) {
            const size_t qrow = qrb + qfin + nt * 16 + l16;
            #pragma unroll
            for (int mt = 0; mt < 4; ++mt) {
                float4 o;
                o.x = oacc[mt][nt][0] * invl[nt];
                o.y = oacc[mt][nt][1] * invl[nt];
                o.z = oacc[mt][nt][2] * invl[nt];
                o.w = oacc[mt][nt][3] * invl[nt];
                *(float4*)&Og[qrow * DH + mt * 16 + quad * 4] = o;
            }
        }
    }
}

extern "C" void kernel_launch(void* const* d_in, const int* in_sizes, int n_in,
                              void* d_out, int out_size, void* d_ws, size_t ws_size,
                              hipStream_t stream) {
    const float* Q = (const float*)d_in[0];
    const float* K = (const float*)d_in[1];
    const float* V = (const float*)d_in[2];
    float* O = (float*)d_out;
    (void)in_sizes; (void)n_in; (void)out_size; (void)ws_size;

    const size_t nelem = (size_t)BHN * T_SEQ * DH;   // 4,194,304
    bf16* Kbf = (bf16*)d_ws;            // 8 MiB
    bf16* Vtb = Kbf + nelem;            // 8 MiB

    prep<<<dim3(1024), dim3(256), 0, stream>>>(K, V, Kbf, Vtb);
    fa_fwd<<<dim3(512), dim3(256), 0, stream>>>(Q, Kbf, Vtb, O);
}

// Round 4
// 120.017 us; speedup vs baseline: 1.0796x; 1.0796x over previous
//
#include <hip/hip_runtime.h>
#include <hip/hip_bf16.h>

// Causal attention, B=2 NH=16 T=2048 D=64, fp32 I/O.
// R16 = R14 skeleton (4 waves, 17/17/16/16 strips, single-V, CEXP-folded Kb,
// setprio, NO forced occupancy bounds) with the P LDS ROUND-TRIP REPLACED by
// an in-register permlane exchange (T12 mechanism, exact lane algebra below):
//   S^T C-layout: lane(quad_s,l16) holds sa[mt][nt][r] = P[key=mt*16+quad_s*4+r][q]
//   PV B-frag:    lane(quad_t,l16) needs P[k=quad_t*8+j][q], j=0..7
//   k = qt*8+j -> mt=qt>>1, quad_s=(qt&1)*2+(j>>2), r=j&3.
//   Pack pairs: X_d = cvtpk(p_mt0[2d],p_mt0[2d+1]), Y_d = cvtpk(p_mt1[...]).
//   permlane32_swap(X,Y): X'={X_lo,Y_lo}, Y'={X_hi,Y_hi}   (mt by half)
//   permlane16_swap(X',Y'): X''={X'0:16,Y'0:16,X'32:48,Y'32:48} = word_d
//                           Y''= the complement              = word_{d+2}
//   -> pfr[nt] = {w0,w1,w2,w3}. Verified at lanes 0/16/32/48/63, words 0-3.
// Removes 8 ds_write + 4 ds_read + lgkm drain per step AND the P/K overlay
// constraint. R15 post-mortem: cross-step pipeline = regression (2nd lgkm
// drain + sa live-range stretch); reverted.

typedef __bf16 bf16;
typedef __bf16 bf16x2 __attribute__((ext_vector_type(2)));
typedef __bf16 bf16x4 __attribute__((ext_vector_type(4)));
typedef __bf16 bf16x8 __attribute__((ext_vector_type(8)));
typedef float floatx4 __attribute__((ext_vector_type(4)));

#define T_SEQ 2048
#define DH 64
#define TKS 32
#define BHN 32
#define CEXP 0.18033688011112042f  // (1/sqrt(64)) * log2(e)

__device__ __forceinline__ void gload16(const bf16* g, bf16* l) {
    __builtin_amdgcn_global_load_lds(
        (const __attribute__((address_space(1))) void*)g,
        (__attribute__((address_space(3))) void*)l, 16, 0, 0);
}

// ---------------- fused prepass (CEXP folded into Kb) ----------------
__global__ __launch_bounds__(256) void prep(const float* __restrict__ K,
                                            const float* __restrict__ V,
                                            bf16* __restrict__ Kb,
                                            bf16* __restrict__ Vt) {
    const int bid = (int)blockIdx.x;
    const int tid = (int)threadIdx.x;
    if (bid < 512) {
        size_t i = ((size_t)bid * 256 + tid) * 8;
        #pragma unroll
        for (int it = 0; it < 4; ++it) {
            float4 a = *(const float4*)(K + i + 0);
            float4 b = *(const float4*)(K + i + 4);
            bf16x8 o;
            o[0]=(bf16)(a.x*CEXP); o[1]=(bf16)(a.y*CEXP); o[2]=(bf16)(a.z*CEXP); o[3]=(bf16)(a.w*CEXP);
            o[4]=(bf16)(b.x*CEXP); o[5]=(bf16)(b.y*CEXP); o[6]=(bf16)(b.z*CEXP); o[7]=(bf16)(b.w*CEXP);
            *(bf16x8*)(Kb + i) = o;
            i += (size_t)512 * 256 * 8;
        }
        return;
    }
    __shared__ bf16 tile[2][64][72];
    const int vb = bid - 512;
    const int bh = vb & (BHN - 1);
    const int tp = (vb >> 5) * 128;
    #pragma unroll
    for (int tt = 0; tt < 2; ++tt) {
        const int r = tid >> 2;
        const int c = (tid & 3) * 16;
        const float* s = V + ((size_t)bh * T_SEQ + tp + tt * 64 + r) * DH + c;
        float4 f0 = *(const float4*)(s + 0);
        float4 f1 = *(const float4*)(s + 4);
        float4 f2 = *(const float4*)(s + 8);
        float4 f3 = *(const float4*)(s + 12);
        bf16x8 p0, p1;
        p0[0]=(bf16)f0.x; p0[1]=(bf16)f0.y; p0[2]=(bf16)f0.z; p0[3]=(bf16)f0.w;
        p0[4]=(bf16)f1.x; p0[5]=(bf16)f1.y; p0[6]=(bf16)f1.z; p0[7]=(bf16)f1.w;
        p1[0]=(bf16)f2.x; p1[1]=(bf16)f2.y; p1[2]=(bf16)f2.z; p1[3]=(bf16)f2.w;
        p1[4]=(bf16)f3.x; p1[5]=(bf16)f3.y; p1[6]=(bf16)f3.z; p1[7]=(bf16)f3.w;
        *(bf16x8*)&tile[tt][r][c + 0] = p0;
        *(bf16x8*)&tile[tt][r][c + 8] = p1;
    }
    __syncthreads();
    #pragma unroll
    for (int tt = 0; tt < 2; ++tt) {
        const int d   = tid >> 2;
        const int tch = (tid & 3) * 16;
        bf16x8 o0, o1;
        #pragma unroll
        for (int j = 0; j < 8; ++j) { o0[j] = tile[tt][tch + j][d]; o1[j] = tile[tt][tch + 8 + j][d]; }
        bf16* o = Vt + ((size_t)bh * DH + d) * T_SEQ + tp + tt * 64 + tch;
        *(bf16x8*)(o + 0) = o0;
        *(bf16x8*)(o + 8) = o1;
    }
}

// ---------------- main flash kernel ----------------
// Per-wave LDS (bf16 elems, 6144 = 12 KB): K0@0, K1@2048, V@4096 (single buf).
// K tile [32 key][64 d]: row = 8x16B chunks, slot c of row r = global chunk c^(r&7).
// V tile [64 d][32 k]: row = 4x16B chunks, slot c of row r = global chunk c^((r>>1)&3).
// MFMA 16x16x32: A[m=l16][k=quad*8+j], B[k=quad*8+j][n=l16], C/D col=l16,row=quad*4+r.
__global__ __launch_bounds__(256, 2)
void fa_fwd(const float* __restrict__ Qg, const bf16* __restrict__ Kb,
            const bf16* __restrict__ Vt, float* __restrict__ Og)
{
    __shared__ __align__(16) bf16 smem[24576];   // 48 KB = 4 waves x 12 KB

    const int gid = (int)blockIdx.x;
    const int bh  = gid & (BHN - 1);
    const int m   = gid >> 5;                    // 0..15
    const int B   = 64 - 2 * m;                  // heavy tile count (>=34)
    const int qh  = (31 - m) * 64;
    const int ql  = m * 64;

    const int tid  = (int)threadIdx.x;
    const int wave = tid >> 6;
    const int lane = tid & 63;
    const int quad = lane >> 4;
    const int l16  = lane & 15;
    const int psw  = (l16 >> 1) & 3;

    const int tw0 = (wave < 2) ? wave * 17 : 34 + (wave - 2) * 16;
    const int tw1 = tw0 + ((wave < 2) ? 17 : 16);

    bf16* W = smem + wave * 6144;

    const bf16* Kbh = Kb + (size_t)bh * (T_SEQ * DH);
    const bf16* Vbh = Vt + (size_t)bh * (DH * T_SEQ);
    const size_t qrb = (size_t)bh * T_SEQ;

    // staging lane constants
    const int rl  = lane >> 3;
    const int kch = (lane & 7) ^ (rl & 7);
    const int vr  = lane >> 2;
    const int vch = (lane & 3) ^ ((lane >> 3) & 3);

    bool heavyNow = (tw0 < B);
    int  qbase    = heavyNow ? qh : ql;
    bool hasPark  = false;

    bf16x8 qb[4][2];
    auto loadQ = [&](int qb0) {
        #pragma unroll
        for (int nt = 0; nt < 4; ++nt) {
            const int qrow = qb0 + nt * 16 + l16;
            #pragma unroll
            for (int kk = 0; kk < 2; ++kk) {
                const float* s = Qg + (qrb + qrow) * DH + kk * 32 + quad * 8;
                float4 f0 = *(const float4*)(s);
                float4 f1 = *(const float4*)(s + 4);
                bf16x8 t;
                t[0]=(bf16)f0.x; t[1]=(bf16)f0.y; t[2]=(bf16)f0.z; t[3]=(bf16)f0.w;
                t[4]=(bf16)f1.x; t[5]=(bf16)f1.y; t[6]=(bf16)f1.z; t[7]=(bf16)f1.w;
                qb[nt][kk] = t;
            }
        }
    };
    loadQ(qbase);

    floatx4 oacc[4][4];
    #pragma unroll
    for (int mt = 0; mt < 4; ++mt)
        #pragma unroll
        for (int nt = 0; nt < 4; ++nt) oacc[mt][nt] = (floatx4){0.f,0.f,0.f,0.f};
    float lpart[4] = {0.f, 0.f, 0.f, 0.f};
    bf16x4 parked[16];
    #pragma unroll
    for (int f = 0; f < 16; ++f) parked[f] = (bf16x4){(bf16)0.f,(bf16)0.f,(bf16)0.f,(bf16)0.f};
    float lpark[4] = {0.f, 0.f, 0.f, 0.f};

    auto kTileOf = [&](int t) { return (t < B) ? t : (t - B); };

    auto stageK = [&](int kt, bf16* dst) {
        const bf16* kg = Kbh + (size_t)kt * TKS * DH;
        #pragma unroll
        for (int g = 0; g < 4; ++g)
            gload16(kg + (size_t)(g * 8 + rl) * DH + kch * 8, dst + g * 512);
    };
    auto stageV = [&](int kt, bf16* dst) {
        const bf16* vg = Vbh + kt * TKS;
        #pragma unroll
        for (int g = 0; g < 4; ++g)
            gload16(vg + (size_t)(g * 16 + vr) * T_SEQ + vch * 8, dst + g * 512);
    };

    // pack 2 fp32 -> 1 dword of 2 bf16 (compiler fuses to v_cvt_pk_bf16_f32)
    auto pk2 = [&](float a, float b) -> unsigned {
        bf16x2 h; h[0] = (bf16)a; h[1] = (bf16)b;
        return __builtin_bit_cast(unsigned, h);
    };

    stageK(kTileOf(tw0), W);
    stageV(kTileOf(tw0), W + 4096);

    for (int t = tw0; t < tw1; ++t) {
        if (heavyNow && t == B) {                // park heavy, switch to light
            #pragma unroll
            for (int f = 0; f < 16; ++f) {
                bf16x4 w;
                #pragma unroll
                for (int e = 0; e < 4; ++e) w[e] = (bf16)oacc[f >> 2][f & 3][e];
                parked[f] = w;
            }
            #pragma unroll
            for (int nt = 0; nt < 4; ++nt) { lpark[nt] = lpart[nt]; lpart[nt] = 0.f; }
            #pragma unroll
            for (int mt = 0; mt < 4; ++mt)
                #pragma unroll
                for (int nt = 0; nt < 4; ++nt) oacc[mt][nt] = (floatx4){0.f,0.f,0.f,0.f};
            hasPark = true;
            heavyNow = false;
            qbase = ql;
            loadQ(ql);
        }

        const int cur = (t - tw0) & 1;
        bf16* Kcur = W + cur * 2048;
        bf16* Vcur = W + 4096;                   // single V buffer
        const int kt = kTileOf(t);
        const int k0 = kt * TKS;

        const bool pf = (t + 1 < tw1);
        if (pf) {                                // prefetch K(t+1) into alt buffer
            stageK(kTileOf(t + 1), W + (cur ^ 1) * 2048);
            __builtin_amdgcn_s_waitcnt(0x0F78);  // vmcnt(8): K(t) landed
        } else {
            __builtin_amdgcn_s_waitcnt(0x0F70);  // vmcnt(0): everything landed
        }

        // ---- S^T = K.Q^T ----
        floatx4 sa[2][4];
        #pragma unroll
        for (int mt = 0; mt < 2; ++mt)
            #pragma unroll
            for (int nt = 0; nt < 4; ++nt) sa[mt][nt] = (floatx4){0.f,0.f,0.f,0.f};
        __builtin_amdgcn_s_setprio(1);
        #pragma unroll
        for (int kk = 0; kk < 2; ++kk) {
            #pragma unroll
            for (int mt = 0; mt < 2; ++mt) {
                bf16x8 kf = *(const bf16x8*)&Kcur[(mt * 16 + l16) * 64 + (((kk * 4 + quad) ^ (l16 & 7)) * 8)];
                #pragma unroll
                for (int nt = 0; nt < 4; ++nt)
                    sa[mt][nt] = __builtin_amdgcn_mfma_f32_16x16x32_bf16(kf, qb[nt][kk], sa[mt][nt], 0, 0, 0);
            }
        }
        __builtin_amdgcn_s_setprio(0);
        // ---- causal mask (diagonal band) ----
        if (k0 + TKS - 1 > qbase) {
            #pragma unroll
            for (int mt = 0; mt < 2; ++mt)
                #pragma unroll
                for (int nt = 0; nt < 4; ++nt) {
                    const int qg = qbase + nt * 16 + l16;
                    #pragma unroll
                    for (int r = 0; r < 4; ++r) {
                        const int keyg = k0 + mt * 16 + quad * 4 + r;
                        if (keyg > qg) sa[mt][nt][r] = -INFINITY;
                    }
                }
        }
        // ---- exp2 + in-register P^T B-fragment build (no LDS round-trip) ----
        bf16x8 pfr[4];
        #pragma unroll
        for (int nt = 0; nt < 4; ++nt) {
            float p0[4], p1[4];
            #pragma unroll
            for (int r = 0; r < 4; ++r) {
                p0[r] = __builtin_amdgcn_exp2f(sa[0][nt][r]);
                p1[r] = __builtin_amdgcn_exp2f(sa[1][nt][r]);
                lpart[nt] += p0[r] + p1[r];
            }
            unsigned X0 = pk2(p0[0], p0[1]);     // mt0, d0
            unsigned X1 = pk2(p0[2], p0[3]);     // mt0, d1
            unsigned Y0 = pk2(p1[0], p1[1]);     // mt1, d0
            unsigned Y1 = pk2(p1[2], p1[3]);     // mt1, d1
            // d=0: -> word0 (X0), word2 (Y0)
            asm("v_permlane32_swap_b32 %0, %1" : "+v"(X0), "+v"(Y0));
            asm("v_permlane16_swap_b32 %0, %1" : "+v"(X0), "+v"(Y0));
            // d=1: -> word1 (X1), word3 (Y1)
            asm("v_permlane32_swap_b32 %0, %1" : "+v"(X1), "+v"(Y1));
            asm("v_permlane16_swap_b32 %0, %1" : "+v"(X1), "+v"(Y1));
            uint4 u; u.x = X0; u.y = X1; u.z = Y0; u.w = Y1;
            pfr[nt] = __builtin_bit_cast(bf16x8, u);
        }
        // ---- V frags to regs, then stage V(t+1) into the SAME buffer ----
        if (pf) __builtin_amdgcn_s_waitcnt(0x0F74);  // vmcnt(4): V(t) landed
        bf16x8 vf[4];
        #pragma unroll
        for (int mt = 0; mt < 4; ++mt)
            vf[mt] = *(const bf16x8*)&Vcur[(mt * 16 + l16) * 32 + ((quad ^ psw) * 8)];
        if (pf) {
            __builtin_amdgcn_s_waitcnt(0xC07F);      // lgkmcnt(0): vf (+kf) in regs
            stageV(kTileOf(t + 1), Vcur);            // safe: V(t) consumed
        }
        // ---- O^T += V^T.P^T ----
        __builtin_amdgcn_s_setprio(1);
        #pragma unroll
        for (int mt = 0; mt < 4; ++mt) {
            #pragma unroll
            for (int nt = 0; nt < 4; ++nt)
                oacc[mt][nt] = __builtin_amdgcn_mfma_f32_16x16x32_bf16(vf[mt], pfr[nt], oacc[mt][nt], 0, 0, 0);
        }
        __builtin_amdgcn_s_setprio(0);
    }

    // ================= end combine (R12-proven layout, fits 48 KB) =========
    __syncthreads();
    const bool hH = (tw0 < B);
    const bool hL = (tw1 > B);
    if (wave >= 1 && hH) {
        bf16* a = smem + (wave - 1) * 4608;
        float* al = (float*)(a + 4096);
        #pragma unroll
        for (int f = 0; f < 16; ++f) {
            bf16x4 w;
            if (hasPark) w = parked[f];
            else {
                #pragma unroll
                for (int e = 0; e < 4; ++e) w[e] = (bf16)oacc[f >> 2][f & 3][e];
            }
            *(bf16x4*)&a[(f * 64 + lane) * 4] = w;
        }
        #pragma unroll
        for (int nt = 0; nt < 4; ++nt)
            al[nt * 64 + lane] = hasPark ? lpark[nt] : lpart[nt];
    }
    if (wave >= 2 && hL) {
        bf16* a = smem + (wave + 1) * 4608;      // wave2->area3, wave3->area4
        float* al = (float*)(a + 4096);
        #pragma unroll
        for (int f = 0; f < 16; ++f) {
            bf16x4 w;
            #pragma unroll
            for (int e = 0; e < 4; ++e) w[e] = (bf16)oacc[f >> 2][f & 3][e];
            *(bf16x4*)&a[(f * 64 + lane) * 4] = w;
        }
        #pragma unroll
        for (int nt = 0; nt < 4; ++nt)
            al[nt * 64 + lane] = lpart[nt];
    }
    __syncthreads();

    if (wave <= 1) {
        int qfin;
        if (wave == 0) {
            qfin = qh;
            const int nA = (B > 50) ? 3 : ((B > 34) ? 2 : 1);
            for (int i = 0; i < nA; ++i) {
                const bf16* a = smem + i * 4608;
                const float* al = (const float*)(a + 4096);
                #pragma unroll
                for (int f = 0; f < 16; ++f) {
                    bf16x4 w = *(const bf16x4*)&a[(f * 64 + lane) * 4];
                    #pragma unroll
                    for (int e = 0; e < 4; ++e) oacc[f >> 2][f & 3][e] += (float)w[e];
                }
                #pragma unroll
                for (int nt = 0; nt < 4; ++nt) lpart[nt] += al[nt * 64 + lane];
            }
        } else {
            qfin = ql;
            #pragma unroll
            for (int mt = 0; mt < 4; ++mt)
                #pragma unroll
                for (int nt = 0; nt < 4; ++nt) oacc[mt][nt] = (floatx4){0.f,0.f,0.f,0.f};
            #pragma unroll
            for (int nt = 0; nt < 4; ++nt) lpart[nt] = 0.f;
            const int i0 = (B < 50) ? 3 : 4;
            for (int i = i0; i <= 4; ++i) {
                const bf16* a = smem + i * 4608;
                const float* al = (const float*)(a + 4096);
                #pragma unroll
                for (int f = 0; f < 16; ++f) {
                    bf16x4 w = *(const bf16x4*)&a[(f * 64 + lane) * 4];
                    #pragma unroll
                    for (int e = 0; e < 4; ++e) oacc[f >> 2][f & 3][e] += (float)w[e];
                }
                #pragma unroll
                for (int nt = 0; nt < 4; ++nt) lpart[nt] += al[nt * 64 + lane];
            }
        }
        float invl[4];
        #pragma unroll
        for (int nt = 0; nt < 4; ++nt) {
            float v = lpart[nt];
            v += __shfl_xor(v, 16);
            v += __shfl_xor(v, 32);
            invl[nt] = 1.0f / v;
        }
        #pragma unroll
        for (int nt = 0; nt < 4; ++nt) {
            const size_t qrow = qrb + qfin + nt * 16 + l16;
            #pragma unroll
            for (int mt = 0; mt < 4; ++mt) {
                float4 o;
                o.x = oacc[mt][nt][0] * invl[nt];
                o.y = oacc[mt][nt][1] * invl[nt];
                o.z = oacc[mt][nt][2] * invl[nt];
                o.w = oacc[mt][nt][3] * invl[nt];
                *(float4*)&Og[qrow * DH + mt * 16 + quad * 4] = o;
            }
        }
    }
}

extern "C" void kernel_launch(void* const* d_in, const int* in_sizes, int n_in,
                              void* d_out, int out_size, void* d_ws, size_t ws_size,
                              hipStream_t stream) {
    const float* Q = (const float*)d_in[0];
    const float* K = (const float*)d_in[1];
    const float* V = (const float*)d_in[2];
    float* O = (float*)d_out;
    (void)in_sizes; (void)n_in; (void)out_size; (void)ws_size;

    const size_t nelem = (size_t)BHN * T_SEQ * DH;   // 4,194,304
    bf16* Kbf = (bf16*)d_ws;            // 8 MiB
    bf16* Vtb = Kbf + nelem;            // 8 MiB

    prep<<<dim3(1024), dim3(256), 0, stream>>>(K, V, Kbf, Vtb);
    fa_fwd<<<dim3(512), dim3(256), 0, stream>>>(Q, Kbf, Vtb, O);
}